// Round 5
// baseline (133.664 us; speedup 1.0000x reference)
//
#include <hip/hip_runtime.h>
#include <math.h>

// Hit-miss transform: out[i][j] = min_{di,dj}(x[i+di][j+dj] - Khit[di][dj])
//                               - max_{di,dj}(x[i+di][j+dj] - Kmiss[di][dj])
// H=W=4096 fp32 input, 5x5 kernels, output 4092x4092 fp32.
//
// R5: LDS-staged tile. R2-R4 showed the compiler pins VGPRs at 32 and
// re-sinks global loads to the consumption points (latency-bound, ~2x ideal
// VALU issue). Instead of fighting the allocator, make re-reads cheap:
// 256x32 output tile staged in LDS (260x36 floats, 37.4 KB), compute reads
// via ds_read_b128 with offset-immediate addressing (LDS pipe, not VALU).
// min/max chains fused via inline v_min3/v_max3 (compiler won't fold fminf
// without nnan).

constexpr int KS = 5;
constexpr int WW = 4096;
constexpr int HH = 4096;
constexpr int HO = 4092;
constexpr int WO = 4092;

constexpr int TW  = 256;          // output tile width
constexpr int TH  = 32;           // output tile height
constexpr int IW  = TW + KS - 1;  // 260 input cols per tile
constexpr int IH  = TH + KS - 1;  // 36 input rows per tile
constexpr int F4W = IW / 4;       // 65 float4 per LDS row
constexpr int NF4 = F4W * IH;     // 2340 float4 to stage

__device__ __forceinline__ float min3f(float a, float b, float c) {
    float d;
    asm("v_min3_f32 %0, %1, %2, %3" : "=v"(d) : "v"(a), "v"(b), "v"(c));
    return d;
}
__device__ __forceinline__ float max3f(float a, float b, float c) {
    float d;
    asm("v_max3_f32 %0, %1, %2, %3" : "=v"(d) : "v"(a), "v"(b), "v"(c));
    return d;
}

__global__ __launch_bounds__(256) void hitmiss_kernel(
    const float* __restrict__ x,
    const float* __restrict__ kh,
    const float* __restrict__ km,
    float* __restrict__ out)
{
    __shared__ __attribute__((aligned(16))) float lds[IW * IH];

    const int tid = threadIdx.x;
    const int c0  = blockIdx.x * TW;   // tile base col (input & output)
    const int r0  = blockIdx.y * TH;   // tile base row (input & output)

    // Kernel weights: uniform addresses -> scalar loads (overlap with staging).
    float wh[KS * KS], wm[KS * KS];
#pragma unroll
    for (int i = 0; i < KS * KS; ++i) {
        wh[i] = kh[i];
        wm[i] = km[i];
    }

    // ---- Stage 260x36 input tile into LDS (coalesced float4) ----
#pragma unroll
    for (int it = 0; it < (NF4 + 255) / 256; ++it) {
        const int f = it * 256 + tid;
        if (f < NF4) {
            const int fr = f / F4W;            // tile row 0..35
            const int fc = (f - fr * F4W) * 4; // tile col (floats) 0..256
            int gr = r0 + fr; if (gr > HH - 1) gr = HH - 1;      // clamp: halo only
            int gc = c0 + fc; if (gc > WW - 4) gc = WW - 4;      // stays 16B-aligned
            const float4 a = *reinterpret_cast<const float4*>(x + (size_t)gr * WW + gc);
            *reinterpret_cast<float4*>(&lds[fr * IW + fc]) = a;
        }
    }
    __syncthreads();

    // ---- Compute: each thread 4 cols x 8 rows ----
    const int tx = tid & 63;          // col group within tile
    const int ty = tid >> 6;          // row group (0..3), 8 rows each
    const int jl = tx * 4;            // tile-local col
    const int jg = c0 + jl;           // global output col
    const bool colok = (jg + 3 < WO); // skip the j>=4092 fringe

#pragma unroll
    for (int orow = 0; orow < TH / 4; ++orow) {
        const int s0 = ty * (TH / 4) + orow;  // tile-local output row

        float mnA[4], mxA[4], mnP[4], mxP[4];

#pragma unroll
        for (int di = 0; di < KS; ++di) {
            const float* lp = &lds[(s0 + di) * IW + jl];
            const float4 a = *reinterpret_cast<const float4*>(lp);
            const float4 b = *reinterpret_cast<const float4*>(lp + 4);
            const float v[8] = {a.x, a.y, a.z, a.w, b.x, b.y, b.z, b.w};
#pragma unroll
            for (int dj = 0; dj < KS; ++dj) {
                const int k = di * KS + dj;
                const float h = wh[k];
                const float m = wm[k];
#pragma unroll
                for (int p = 0; p < 4; ++p) {
                    const float t  = v[dj + p];
                    const float th = t - h;
                    const float tm = t - m;
                    if (k == 0) {
                        mnA[p] = th; mxA[p] = tm;
                    } else if (k & 1) {
                        mnP[p] = th; mxP[p] = tm;
                    } else {
                        // fold pending + current: 12 min3 + 12 max3 per pixel
                        mnA[p] = min3f(mnA[p], mnP[p], th);
                        mxA[p] = max3f(mxA[p], mxP[p], tm);
                    }
                }
            }
        }

        const int og = r0 + s0;       // global output row
        if (colok && og < HO) {
            float4 o;
            o.x = mnA[0] - mxA[0];
            o.y = mnA[1] - mxA[1];
            o.z = mnA[2] - mxA[2];
            o.w = mnA[3] - mxA[3];
            *reinterpret_cast<float4*>(out + (size_t)og * WO + jg) = o;
        }
    }
}

extern "C" void kernel_launch(void* const* d_in, const int* in_sizes, int n_in,
                              void* d_out, int out_size, void* d_ws, size_t ws_size,
                              hipStream_t stream) {
    const float* x  = (const float*)d_in[0];
    const float* kh = (const float*)d_in[1];
    const float* km = (const float*)d_in[2];
    float* out = (float*)d_out;

    dim3 block(256, 1, 1);
    dim3 grid((WO + TW - 1) / TW, (HO + TH - 1) / TH, 1);  // 16 x 128
    hipLaunchKernelGGL(hitmiss_kernel, grid, block, 0, stream, x, kh, km, out);
}

// Round 6
// 126.784 us; speedup vs baseline: 1.0543x; 1.0543x over previous
//
#include <hip/hip_runtime.h>
#include <math.h>

// Hit-miss transform: out[i][j] = min_{di,dj}(x[i+di][j+dj] - Khit[di][dj])
//                               - max_{di,dj}(x[i+di][j+dj] - Kmiss[di][dj])
// H=W=4096 fp32 input, 5x5 kernels, output 4092x4092 fp32.
//
// R6: async LDS staging. R2/R4 are latency-bound: the allocator pins VGPRs
// at 32 and convoys global loads. global_load_lds (width=16) DMAs straight
// to LDS with no dest VGPRs; one vmcnt drain at the barrier. 256x16 output
// tile = 260x20 input = 24.6 KB LDS (padded to 6x256 f4 chunks so every
// lane always issues -> no exec-mask edge cases) -> ~6 blocks/CU.
// LDS-dest rule: wave-uniform base + lane*16; per-lane addressing only on
// the global side (edge-clamped, 16B-aligned). Compute reads ds_read_b128
// off one base reg + immediate offsets. min3/max3 via inline asm.

constexpr int KS = 5;
constexpr int WW = 4096;
constexpr int HH = 4096;
constexpr int HO = 4092;
constexpr int WO = 4092;

constexpr int TW   = 256;          // output tile width
constexpr int TH   = 16;           // output tile height
constexpr int IW   = TW + KS - 1;  // 260 input cols
constexpr int IH   = TH + KS - 1;  // 20 input rows
constexpr int F4W  = IW / 4;       // 65 float4 per input row
constexpr int NF4  = F4W * IH;     // 1300 float4 useful
constexpr int NF4P = 1536;         // padded to 6 * 256 (whole wave-chunks)

__device__ __forceinline__ float min3f(float a, float b, float c) {
    float d;
    asm("v_min3_f32 %0, %1, %2, %3" : "=v"(d) : "v"(a), "v"(b), "v"(c));
    return d;
}
__device__ __forceinline__ float max3f(float a, float b, float c) {
    float d;
    asm("v_max3_f32 %0, %1, %2, %3" : "=v"(d) : "v"(a), "v"(b), "v"(c));
    return d;
}

typedef __attribute__((address_space(1))) const void gvoid;
typedef __attribute__((address_space(3))) void svoid;

__global__ __launch_bounds__(256) void hitmiss_kernel(
    const float* __restrict__ x,
    const float* __restrict__ kh,
    const float* __restrict__ km,
    float* __restrict__ out)
{
    __shared__ __attribute__((aligned(16))) float lds[NF4P * 4];  // 24.6 KB

    const int tid = threadIdx.x;
    const int c0  = blockIdx.x * TW;
    const int r0  = blockIdx.y * TH;

    // Kernel weights: uniform addresses -> scalar loads (overlap with DMA).
    float wh[KS * KS], wm[KS * KS];
#pragma unroll
    for (int i = 0; i < KS * KS; ++i) {
        wh[i] = kh[i];
        wm[i] = km[i];
    }

    // ---- Async stage 260x20 tile into LDS ----
    // lds float4 index f <-> tile (fr = f/65, fc = (f%65)*4); linear layout
    // means LDS row stride is exactly IW=260 floats.
    const int w = tid >> 6;            // wave id 0..3
#pragma unroll
    for (int it = 0; it < NF4P / 256; ++it) {   // 6 iterations
        const int f = it * 256 + tid;           // 0..1535, every lane live
        int fr = f / F4W;
        int fc = (f - fr * F4W) * 4;
        if (fr > IH - 1) fr = IH - 1;           // pad chunks re-read last row
        int gr = r0 + fr; if (gr > HH - 1) gr = HH - 1;
        int gc = c0 + fc; if (gc > WW - 4) gc = WW - 4;   // stays 16B-aligned
        const float* gp = x + (size_t)gr * WW + gc;
        // wave-uniform LDS base; HW adds lane*16B -> lds[f*4]
        float* lb = &lds[(it * 4 + w) * 256];
        __builtin_amdgcn_global_load_lds((gvoid*)gp, (svoid*)lb, 16, 0, 0);
    }
    __syncthreads();   // compiler emits s_waitcnt vmcnt(0) before s_barrier

    // ---- Compute: each thread 4 cols x 4 rows ----
    const int tx = tid & 63;
    const int ty = tid >> 6;
    const int jl = tx * 4;
    const int jg = c0 + jl;
    const bool colok = (jg <= WO - 4);

#pragma unroll
    for (int orow = 0; orow < 4; ++orow) {
        const int s = ty * 4 + orow;           // tile-local output row 0..15

        float mnA[4], mxA[4], mnP[4], mxP[4];

#pragma unroll
        for (int di = 0; di < KS; ++di) {
            const float* lp = &lds[(s + di) * IW + jl];
            const float4 a = *reinterpret_cast<const float4*>(lp);
            const float4 b = *reinterpret_cast<const float4*>(lp + 4);
            const float v[8] = {a.x, a.y, a.z, a.w, b.x, b.y, b.z, b.w};
#pragma unroll
            for (int dj = 0; dj < KS; ++dj) {
                const int k = di * KS + dj;
                const float h = wh[k];
                const float m = wm[k];
#pragma unroll
                for (int p = 0; p < 4; ++p) {
                    const float t  = v[dj + p];
                    const float th = t - h;
                    const float tm = t - m;
                    if (k == 0) {
                        mnA[p] = th; mxA[p] = tm;
                    } else if (k & 1) {
                        mnP[p] = th; mxP[p] = tm;
                    } else {
                        mnA[p] = min3f(mnA[p], mnP[p], th);
                        mxA[p] = max3f(mxA[p], mxP[p], tm);
                    }
                }
            }
        }

        const int og = r0 + s;
        if (colok && og < HO) {
            float4 o;
            o.x = mnA[0] - mxA[0];
            o.y = mnA[1] - mxA[1];
            o.z = mnA[2] - mxA[2];
            o.w = mnA[3] - mxA[3];
            *reinterpret_cast<float4*>(out + (size_t)og * WO + jg) = o;
        }
    }
}

extern "C" void kernel_launch(void* const* d_in, const int* in_sizes, int n_in,
                              void* d_out, int out_size, void* d_ws, size_t ws_size,
                              hipStream_t stream) {
    const float* x  = (const float*)d_in[0];
    const float* kh = (const float*)d_in[1];
    const float* km = (const float*)d_in[2];
    float* out = (float*)d_out;

    dim3 block(256, 1, 1);
    dim3 grid((WO + TW - 1) / TW, (HO + TH - 1) / TH, 1);  // 16 x 256
    hipLaunchKernelGGL(hitmiss_kernel, grid, block, 0, stream, x, kh, km, out);
}